// Round 1
// baseline (529.222 us; speedup 1.0000x reference)
//
#include <hip/hip_runtime.h>
#include <hip/hip_bf16.h>
#include <stdint.h>

typedef unsigned short u16;
typedef __attribute__((ext_vector_type(8))) __bf16 bf16x8;
typedef __attribute__((ext_vector_type(4))) float f32x4;

#define BN_EPS 1e-5f
#define MROWS 65536
#define INV_M (1.0f / 65536.0f)

__device__ __forceinline__ u16 f2bf(float f) {
  unsigned u = __builtin_bit_cast(unsigned, f);
  unsigned r = (u + 0x7FFFu + ((u >> 16) & 1u)) >> 16;
  return (u16)r;
}
__device__ __forceinline__ float bf2f(u16 h) {
  return __builtin_bit_cast(float, (unsigned)h << 16);
}

// ------------- layer-0 stats + fp32->bf16 cast: x [65536,256] -------------
// 512 blocks x 256 thr; each block owns 128 rows. Thread t: cols [4*(t&63)..+4), row-phase t>>6.
__global__ __launch_bounds__(256)
void stats_cast_k(const float* __restrict__ x, u16* __restrict__ xbf,
                  float* __restrict__ ssum, float* __restrict__ ssq) {
  const int t = threadIdx.x;
  const int tc = t & 63, tr = t >> 6;
  const int r0 = blockIdx.x * 128;
  float s0 = 0, s1 = 0, s2 = 0, s3 = 0, q0 = 0, q1 = 0, q2 = 0, q3 = 0;
  for (int r = r0 + tr; r < r0 + 128; r += 4) {
    float4 v = *(const float4*)(x + (size_t)r * 256 + tc * 4);
    ushort4 ov;
    ov.x = f2bf(v.x); ov.y = f2bf(v.y); ov.z = f2bf(v.z); ov.w = f2bf(v.w);
    *(ushort4*)(xbf + (size_t)r * 256 + tc * 4) = ov;
    s0 += v.x; q0 += v.x * v.x;
    s1 += v.y; q1 += v.y * v.y;
    s2 += v.z; q2 += v.z * v.z;
    s3 += v.w; q3 += v.w * v.w;
  }
  __shared__ float red[4][256];
  red[tr][tc * 4 + 0] = s0; red[tr][tc * 4 + 1] = s1;
  red[tr][tc * 4 + 2] = s2; red[tr][tc * 4 + 3] = s3;
  __syncthreads();
  if (tr == 0) {
#pragma unroll
    for (int i = 0; i < 4; ++i) {
      int c = tc * 4 + i;
      atomicAdd(&ssum[c], red[0][c] + red[1][c] + red[2][c] + red[3][c]);
    }
  }
  __syncthreads();
  red[tr][tc * 4 + 0] = q0; red[tr][tc * 4 + 1] = q1;
  red[tr][tc * 4 + 2] = q2; red[tr][tc * 4 + 3] = q3;
  __syncthreads();
  if (tr == 0) {
#pragma unroll
    for (int i = 0; i < 4; ++i) {
      int c = tc * 4 + i;
      atomicAdd(&ssq[c], red[0][c] + red[1][c] + red[2][c] + red[3][c]);
    }
  }
}

// ------------- stats over bf16 activations y [65536,512] -------------
__global__ __launch_bounds__(256)
void stats_bf16_k(const u16* __restrict__ y,
                  float* __restrict__ ssum, float* __restrict__ ssq) {
  const int t = threadIdx.x;
  const int tc = t & 63, tr = t >> 6;
  const int r0 = blockIdx.x * 128;
  float s[8] = {}, q[8] = {};
  for (int r = r0 + tr; r < r0 + 128; r += 4) {
    const u16* p = y + (size_t)r * 512 + tc * 8;
    ushort4 a = *(const ushort4*)p;
    ushort4 b = *(const ushort4*)(p + 4);
    float v[8] = {bf2f(a.x), bf2f(a.y), bf2f(a.z), bf2f(a.w),
                  bf2f(b.x), bf2f(b.y), bf2f(b.z), bf2f(b.w)};
#pragma unroll
    for (int i = 0; i < 8; ++i) { s[i] += v[i]; q[i] += v[i] * v[i]; }
  }
  __shared__ float red[4][512];
#pragma unroll
  for (int i = 0; i < 8; ++i) red[tr][tc * 8 + i] = s[i];
  __syncthreads();
  if (tr == 0) {
#pragma unroll
    for (int i = 0; i < 8; ++i) {
      int c = tc * 8 + i;
      atomicAdd(&ssum[c], red[0][c] + red[1][c] + red[2][c] + red[3][c]);
    }
  }
  __syncthreads();
#pragma unroll
  for (int i = 0; i < 8; ++i) red[tr][tc * 8 + i] = q[i];
  __syncthreads();
  if (tr == 0) {
#pragma unroll
    for (int i = 0; i < 8; ++i) {
      int c = tc * 8 + i;
      atomicAdd(&ssq[c], red[0][c] + red[1][c] + red[2][c] + red[3][c]);
    }
  }
}

// ------------- fold BN into weights: W'[o,d]=bf16(W*alpha_d), c'[o]=c+W[o,:]·beta -------------
__global__ __launch_bounds__(256)
void prep_w_k(const float* __restrict__ W, const float* __restrict__ g,
              const float* __restrict__ b, const float* __restrict__ c,
              const float* __restrict__ ssum, const float* __restrict__ ssq,
              u16* __restrict__ Wp, float* __restrict__ cp, int din) {
  const int o = blockIdx.x, t = threadIdx.x;
  float acc = 0.f;
  for (int d = t; d < din; d += 256) {
    float mean = ssum[d] * INV_M;
    float var = ssq[d] * INV_M - mean * mean;
    float alpha = g[d] * rsqrtf(var + BN_EPS);
    float beta = b[d] - mean * alpha;
    float w = W[(size_t)o * din + d];
    Wp[(size_t)o * din + d] = f2bf(w * alpha);
    acc += w * beta;
  }
#pragma unroll
  for (int off = 32; off > 0; off >>= 1) acc += __shfl_down(acc, off, 64);
  __shared__ float wsum[4];
  if ((t & 63) == 0) wsum[t >> 6] = acc;
  __syncthreads();
  if (t == 0) cp[o] = c[o] + wsum[0] + wsum[1] + wsum[2] + wsum[3];
}

// ------------- GEMM: Y = act(A @ B^T + c'), A:[65536,K] bf16, B:[N,K] bf16 -------------
// 128x128 tile, BK=64, 4 waves (2x2), 16x16x32 bf16 MFMA, global_load_lds width-16.
#define GLDS16(gp, lp) __builtin_amdgcn_global_load_lds( \
    (__attribute__((address_space(1))) void*)(void*)(gp), \
    (__attribute__((address_space(3))) void*)(lp), 16, 0, 0)

template <bool RELU, bool DOMAX>
__global__ __launch_bounds__(256)
void gemm_k(const u16* __restrict__ A, const u16* __restrict__ B,
            const float* __restrict__ cp, u16* __restrict__ Y,
            unsigned* __restrict__ maxbuf, int K, int N) {
  __shared__ __align__(16) u16 lds[2 * 128 * 64];
  const int t = threadIdx.x;
  const int w = t >> 6, l = t & 63;
  const int lr = l & 15, lk = l >> 4;
  const int tiles_n = N >> 7;
  const int tm0 = (int)(blockIdx.x / tiles_n) << 7;
  const int tn0 = (int)(blockIdx.x % tiles_n) << 7;
  const int wm = w >> 1, wn = w & 1;

  // staging geometry: per round 256 thr x 16B = 32 rows of [128B]
  const int offb = t << 4;
  const int srow = offb >> 7;
  const int scol = (offb & 127) >> 1;
  const u16* Ab = A + (size_t)(tm0 + srow) * K + scol;
  const u16* Bb = B + (size_t)(tn0 + srow) * K + scol;
  u16* ldsA = lds;
  u16* ldsB = lds + 128 * 64;

  f32x4 acc[4][4] = {};

  const int nk = K >> 6;
  for (int kt = 0; kt < nk; ++kt) {
    const size_t ko = (size_t)kt * 64;
#pragma unroll
    for (int r = 0; r < 4; ++r) {
      GLDS16(Ab + (size_t)r * 32 * K + ko, ldsA + r * 2048 + t * 8);
      GLDS16(Bb + (size_t)r * 32 * K + ko, ldsB + r * 2048 + t * 8);
    }
    __syncthreads();
#pragma unroll
    for (int kk = 0; kk < 2; ++kk) {
      const int k0 = kk * 32 + lk * 8;
      bf16x8 af[4], bfv[4];
#pragma unroll
      for (int m = 0; m < 4; ++m)
        af[m] = *(const bf16x8*)(ldsA + (wm * 64 + m * 16 + lr) * 64 + k0);
#pragma unroll
      for (int n = 0; n < 4; ++n)
        bfv[n] = *(const bf16x8*)(ldsB + (wn * 64 + n * 16 + lr) * 64 + k0);
#pragma unroll
      for (int m = 0; m < 4; ++m)
#pragma unroll
        for (int n = 0; n < 4; ++n)
          acc[m][n] = __builtin_amdgcn_mfma_f32_16x16x32_bf16(af[m], bfv[n], acc[m][n], 0, 0, 0);
    }
    __syncthreads();
  }

  if (!DOMAX) {
#pragma unroll
    for (int m = 0; m < 4; ++m) {
      const int grow = tm0 + wm * 64 + m * 16 + lk * 4;
#pragma unroll
      for (int n = 0; n < 4; ++n) {
        const int gcol = tn0 + wn * 64 + n * 16 + lr;
        const float cb = cp[gcol];
#pragma unroll
        for (int r = 0; r < 4; ++r) {
          float v = acc[m][n][r] + cb;
          if (RELU) v = fmaxf(v, 0.f);
          Y[(size_t)(grow + r) * N + gcol] = f2bf(v);
        }
      }
    }
  } else {
    // max-over-set epilogue: tile fully inside one batch (2048 % 128 == 0)
    const int batch = tm0 >> 11;
#pragma unroll
    for (int n = 0; n < 4; ++n) {
      const int gcol = tn0 + wn * 64 + n * 16 + lr;
      const float cb = cp[gcol];
      float mx = -3.0e38f;
#pragma unroll
      for (int m = 0; m < 4; ++m)
#pragma unroll
        for (int r = 0; r < 4; ++r)
          mx = fmaxf(mx, acc[m][n][r] + cb);
      mx = fmaxf(mx, __shfl_xor(mx, 16, 64));
      mx = fmaxf(mx, __shfl_xor(mx, 32, 64));
      if (lk == 0) {
        unsigned u = __builtin_bit_cast(unsigned, mx);
        u = (u & 0x80000000u) ? ~u : (u | 0x80000000u);
        atomicMax(&maxbuf[batch * N + gcol], u);
      }
    }
  }
}

__global__ void decode_k(const unsigned* __restrict__ mb, float* __restrict__ out, int n) {
  int i = blockIdx.x * 256 + threadIdx.x;
  if (i < n) {
    unsigned u = mb[i];
    u = (u & 0x80000000u) ? (u & 0x7FFFFFFFu) : ~u;
    out[i] = __builtin_bit_cast(float, u);
  }
}

extern "C" void kernel_launch(void* const* d_in, const int* in_sizes, int n_in,
                              void* d_out, int out_size, void* d_ws, size_t ws_size,
                              hipStream_t stream) {
  const float* x0 = (const float*)d_in[0];
  const float* g0 = (const float*)d_in[1];
  const float* b0 = (const float*)d_in[2];
  const float* W0 = (const float*)d_in[3];
  const float* c0 = (const float*)d_in[4];
  const float* g1 = (const float*)d_in[5];
  const float* b1 = (const float*)d_in[6];
  const float* W1 = (const float*)d_in[7];
  const float* c1 = (const float*)d_in[8];
  const float* g2 = (const float*)d_in[9];
  const float* b2 = (const float*)d_in[10];
  const float* W2 = (const float*)d_in[11];
  const float* c2 = (const float*)d_in[12];

  char* ws = (char*)d_ws;
  size_t off = 0;
  auto alloc = [&](size_t bytes) -> char* {
    char* p = ws + off;
    off += (bytes + 255) & ~(size_t)255;
    return p;
  };
  u16* x0bf = (u16*)alloc((size_t)MROWS * 256 * 2);
  u16* y1 = (u16*)alloc((size_t)MROWS * 512 * 2);
  u16* y2 = (u16*)alloc((size_t)MROWS * 512 * 2);
  // contiguous zero-init region: stats0 (512f) | stats1 (1024f) | stats2 (1024f) | maxbuf (32768u)
  float* s0sum = (float*)alloc((512 + 1024 + 1024 + 32768) * 4);
  float* s0sq = s0sum + 256;
  float* s1sum = s0sum + 512;
  float* s1sq = s1sum + 512;
  float* s2sum = s1sum + 1024;
  float* s2sq = s2sum + 512;
  unsigned* maxbuf = (unsigned*)(s0sum + 2560);
  const size_t zbytes = (size_t)(2560 + 32768) * 4;
  u16* W0p = (u16*)alloc(512 * 256 * 2);
  u16* W1p = (u16*)alloc(512 * 512 * 2);
  u16* W2p = (u16*)alloc(1024 * 512 * 2);
  float* c0p = (float*)alloc(512 * 4);
  float* c1p = (float*)alloc(512 * 4);
  float* c2p = (float*)alloc(1024 * 4);
  if (off > ws_size) return;  // workspace too small: bail loudly (validation will fail)

  hipMemsetAsync(s0sum, 0, zbytes, stream);

  // layer 0
  stats_cast_k<<<512, 256, 0, stream>>>(x0, x0bf, s0sum, s0sq);
  prep_w_k<<<512, 256, 0, stream>>>(W0, g0, b0, c0, s0sum, s0sq, W0p, c0p, 256);
  gemm_k<true, false><<<512 * 4, 256, 0, stream>>>(x0bf, W0p, c0p, y1, nullptr, 256, 512);
  // layer 1
  stats_bf16_k<<<512, 256, 0, stream>>>(y1, s1sum, s1sq);
  prep_w_k<<<512, 256, 0, stream>>>(W1, g1, b1, c1, s1sum, s1sq, W1p, c1p, 512);
  gemm_k<true, false><<<512 * 4, 256, 0, stream>>>(y1, W1p, c1p, y2, nullptr, 512, 512);
  // layer 2 + max reduction
  stats_bf16_k<<<512, 256, 0, stream>>>(y2, s2sum, s2sq);
  prep_w_k<<<1024, 256, 0, stream>>>(W2, g2, b2, c2, s2sum, s2sq, W2p, c2p, 512);
  gemm_k<false, true><<<512 * 8, 256, 0, stream>>>(y2, W2p, c2p, nullptr, maxbuf, 512, 1024);
  decode_k<<<128, 256, 0, stream>>>(maxbuf, (float*)d_out, 32768);
}

// Round 2
// 267.020 us; speedup vs baseline: 1.9820x; 1.9820x over previous
//
#include <hip/hip_runtime.h>
#include <hip/hip_bf16.h>
#include <stdint.h>

typedef unsigned short u16;
typedef __attribute__((ext_vector_type(8))) __bf16 bf16x8;
typedef __attribute__((ext_vector_type(4))) float f32x4;

#define BN_EPS 1e-5f
#define MROWS 65536
#define INV_M (1.0f / 65536.0f)

__device__ __forceinline__ u16 f2bf(float f) {
  unsigned u = __builtin_bit_cast(unsigned, f);
  unsigned r = (u + 0x7FFFu + ((u >> 16) & 1u)) >> 16;
  return (u16)r;
}
__device__ __forceinline__ float bf2f(u16 h) {
  return __builtin_bit_cast(float, (unsigned)h << 16);
}

// ------------- layer-0 stats + fp32->bf16 cast: x [65536,256] -------------
__global__ __launch_bounds__(256)
void stats_cast_k(const float* __restrict__ x, u16* __restrict__ xbf,
                  float* __restrict__ ssum, float* __restrict__ ssq) {
  const int t = threadIdx.x;
  const int tc = t & 63, tr = t >> 6;
  const int r0 = blockIdx.x * 128;
  float s0 = 0, s1 = 0, s2 = 0, s3 = 0, q0 = 0, q1 = 0, q2 = 0, q3 = 0;
  for (int r = r0 + tr; r < r0 + 128; r += 4) {
    float4 v = *(const float4*)(x + (size_t)r * 256 + tc * 4);
    ushort4 ov;
    ov.x = f2bf(v.x); ov.y = f2bf(v.y); ov.z = f2bf(v.z); ov.w = f2bf(v.w);
    *(ushort4*)(xbf + (size_t)r * 256 + tc * 4) = ov;
    s0 += v.x; q0 += v.x * v.x;
    s1 += v.y; q1 += v.y * v.y;
    s2 += v.z; q2 += v.z * v.z;
    s3 += v.w; q3 += v.w * v.w;
  }
  __shared__ float red[4][256];
  red[tr][tc * 4 + 0] = s0; red[tr][tc * 4 + 1] = s1;
  red[tr][tc * 4 + 2] = s2; red[tr][tc * 4 + 3] = s3;
  __syncthreads();
  if (tr == 0) {
#pragma unroll
    for (int i = 0; i < 4; ++i) {
      int c = tc * 4 + i;
      atomicAdd(&ssum[c], red[0][c] + red[1][c] + red[2][c] + red[3][c]);
    }
  }
  __syncthreads();
  red[tr][tc * 4 + 0] = q0; red[tr][tc * 4 + 1] = q1;
  red[tr][tc * 4 + 2] = q2; red[tr][tc * 4 + 3] = q3;
  __syncthreads();
  if (tr == 0) {
#pragma unroll
    for (int i = 0; i < 4; ++i) {
      int c = tc * 4 + i;
      atomicAdd(&ssq[c], red[0][c] + red[1][c] + red[2][c] + red[3][c]);
    }
  }
}

// ------------- fold BN into weights: W'[o,d]=bf16(W*alpha_d), c'[o]=c+W[o,:]·beta -------------
__global__ __launch_bounds__(256)
void prep_w_k(const float* __restrict__ W, const float* __restrict__ g,
              const float* __restrict__ b, const float* __restrict__ c,
              const float* __restrict__ ssum, const float* __restrict__ ssq,
              u16* __restrict__ Wp, float* __restrict__ cp, int din) {
  const int o = blockIdx.x, t = threadIdx.x;
  float acc = 0.f;
  for (int d = t; d < din; d += 256) {
    float mean = ssum[d] * INV_M;
    float var = ssq[d] * INV_M - mean * mean;
    float alpha = g[d] * rsqrtf(var + BN_EPS);
    float beta = b[d] - mean * alpha;
    float w = W[(size_t)o * din + d];
    Wp[(size_t)o * din + d] = f2bf(w * alpha);
    acc += w * beta;
  }
#pragma unroll
  for (int off = 32; off > 0; off >>= 1) acc += __shfl_down(acc, off, 64);
  __shared__ float wsum[4];
  if ((t & 63) == 0) wsum[t >> 6] = acc;
  __syncthreads();
  if (t == 0) cp[o] = c[o] + wsum[0] + wsum[1] + wsum[2] + wsum[3];
}

// ------------- GEMM: Y = act(A @ B^T + c'), A:[65536,K] bf16, B:[N,K] bf16 -------------
// 128x128 tile, BK=64, 4 waves (2x2), 16x16x32 bf16 MFMA.
// 2-phase pipelined: double-buffered LDS, STAGE(t+1) issued before compute(t),
// one barrier per K-tile. XCD-swizzled blockIdx. RELU path fuses per-column
// sum/sumsq (BN stats of the NEXT layer) into the epilogue.
#define GLDS16(gp, lp) __builtin_amdgcn_global_load_lds( \
    (__attribute__((address_space(1))) void*)(void*)(gp), \
    (__attribute__((address_space(3))) void*)(lp), 16, 0, 0)

#define STAGE(buf, kt_) do { \
    const size_t ko_ = (size_t)(kt_) * 64; \
    u16* la_ = lds + (buf) * 16384; \
    u16* lb_ = la_ + 8192; \
    _Pragma("unroll") \
    for (int r_ = 0; r_ < 4; ++r_) { \
      GLDS16(Ab + (size_t)r_ * 32 * K + ko_, la_ + r_ * 2048 + t * 8); \
      GLDS16(Bb + (size_t)r_ * 32 * K + ko_, lb_ + r_ * 2048 + t * 8); \
    } \
  } while (0)

template <bool RELU, bool DOMAX>
__global__ __launch_bounds__(256)
void gemm_k(const u16* __restrict__ A, const u16* __restrict__ B,
            const float* __restrict__ cp, u16* __restrict__ Y,
            float* __restrict__ osum, float* __restrict__ osq,
            unsigned* __restrict__ maxbuf, int K, int N) {
  __shared__ __align__(16) u16 lds[2 * 2 * 128 * 64];  // 64 KB: 2 bufs x (A,B) x 128x64
  const int t = threadIdx.x;
  const int w = t >> 6, l = t & 63;
  const int lr = l & 15, lk = l >> 4;

  // XCD-aware bijective swizzle (gridDim.x % 8 == 0 for all our launches)
  const int cpx = (int)gridDim.x >> 3;
  int bid = (int)blockIdx.x;
  bid = (bid & 7) * cpx + (bid >> 3);

  const int tiles_n = N >> 7;
  const int tm0 = (bid / tiles_n) << 7;
  const int tn0 = (bid % tiles_n) << 7;
  const int wm = w >> 1, wn = w & 1;

  // staging geometry: per round 256 thr x 16B = 32 rows of [128B]
  const int offb = t << 4;
  const int srow = offb >> 7;
  const int scol = (offb & 127) >> 1;
  const u16* Ab = A + (size_t)(tm0 + srow) * K + scol;
  const u16* Bb = B + (size_t)(tn0 + srow) * K + scol;

  f32x4 acc[4][4] = {};

  const int nk = K >> 6;
  int cur = 0;
  STAGE(0, 0);
  for (int kt = 0; kt < nk; ++kt) {
    __syncthreads();  // drains own vmcnt (stage into buf[cur] done) + syncs waves
    if (kt + 1 < nk) STAGE(cur ^ 1, kt + 1);
    const u16* la = lds + cur * 16384;
    const u16* lb = la + 8192;
#pragma unroll
    for (int kk = 0; kk < 2; ++kk) {
      const int k0 = kk * 32 + lk * 8;
      bf16x8 af[4], bfv[4];
#pragma unroll
      for (int m = 0; m < 4; ++m)
        af[m] = *(const bf16x8*)(la + (wm * 64 + m * 16 + lr) * 64 + k0);
#pragma unroll
      for (int n = 0; n < 4; ++n)
        bfv[n] = *(const bf16x8*)(lb + (wn * 64 + n * 16 + lr) * 64 + k0);
#pragma unroll
      for (int m = 0; m < 4; ++m)
#pragma unroll
        for (int n = 0; n < 4; ++n)
          acc[m][n] = __builtin_amdgcn_mfma_f32_16x16x32_bf16(af[m], bfv[n], acc[m][n], 0, 0, 0);
    }
    cur ^= 1;
  }

  if (!DOMAX) {
    float cs[4] = {}, cq[4] = {};
#pragma unroll
    for (int m = 0; m < 4; ++m) {
      const int grow = tm0 + wm * 64 + m * 16 + lk * 4;
#pragma unroll
      for (int n = 0; n < 4; ++n) {
        const int gcol = tn0 + wn * 64 + n * 16 + lr;
        const float cb = cp[gcol];
#pragma unroll
        for (int r = 0; r < 4; ++r) {
          float v = acc[m][n][r] + cb;
          if (RELU) v = fmaxf(v, 0.f);
          Y[(size_t)(grow + r) * N + gcol] = f2bf(v);
          cs[n] += v;
          cq[n] += v * v;
        }
      }
    }
    if (RELU) {
      // reduce over lk (lanes lr+16*lk): xor 16, 32
#pragma unroll
      for (int n = 0; n < 4; ++n) {
        cs[n] += __shfl_xor(cs[n], 16, 64);
        cs[n] += __shfl_xor(cs[n], 32, 64);
        cq[n] += __shfl_xor(cq[n], 16, 64);
        cq[n] += __shfl_xor(cq[n], 32, 64);
      }
      float* sred = (float*)lds;  // [0..255]=sum (wm-major), [256..511]=sumsq
      __syncthreads();            // all waves done with fragment LDS
      if (lk == 0) {
#pragma unroll
        for (int n = 0; n < 4; ++n) {
          const int c = wn * 64 + n * 16 + lr;
          sred[wm * 128 + c] = cs[n];
          sred[256 + wm * 128 + c] = cq[n];
        }
      }
      __syncthreads();
      if (t < 128) {
        atomicAdd(&osum[tn0 + t], sred[t] + sred[128 + t]);
        atomicAdd(&osq[tn0 + t], sred[256 + t] + sred[384 + t]);
      }
    }
  } else {
    // max-over-set epilogue: tile fully inside one batch (2048 % 128 == 0)
    const int batch = tm0 >> 11;
#pragma unroll
    for (int n = 0; n < 4; ++n) {
      const int gcol = tn0 + wn * 64 + n * 16 + lr;
      const float cb = cp[gcol];
      float mx = -3.0e38f;
#pragma unroll
      for (int m = 0; m < 4; ++m)
#pragma unroll
        for (int r = 0; r < 4; ++r)
          mx = fmaxf(mx, acc[m][n][r] + cb);
      mx = fmaxf(mx, __shfl_xor(mx, 16, 64));
      mx = fmaxf(mx, __shfl_xor(mx, 32, 64));
      if (lk == 0) {
        unsigned u = __builtin_bit_cast(unsigned, mx);
        u = (u & 0x80000000u) ? ~u : (u | 0x80000000u);
        atomicMax(&maxbuf[batch * N + gcol], u);
      }
    }
  }
}

__global__ void decode_k(const unsigned* __restrict__ mb, float* __restrict__ out, int n) {
  int i = blockIdx.x * 256 + threadIdx.x;
  if (i < n) {
    unsigned u = mb[i];
    u = (u & 0x80000000u) ? (u & 0x7FFFFFFFu) : ~u;
    out[i] = __builtin_bit_cast(float, u);
  }
}

extern "C" void kernel_launch(void* const* d_in, const int* in_sizes, int n_in,
                              void* d_out, int out_size, void* d_ws, size_t ws_size,
                              hipStream_t stream) {
  const float* x0 = (const float*)d_in[0];
  const float* g0 = (const float*)d_in[1];
  const float* b0 = (const float*)d_in[2];
  const float* W0 = (const float*)d_in[3];
  const float* c0 = (const float*)d_in[4];
  const float* g1 = (const float*)d_in[5];
  const float* b1 = (const float*)d_in[6];
  const float* W1 = (const float*)d_in[7];
  const float* c1 = (const float*)d_in[8];
  const float* g2 = (const float*)d_in[9];
  const float* b2 = (const float*)d_in[10];
  const float* W2 = (const float*)d_in[11];
  const float* c2 = (const float*)d_in[12];

  char* ws = (char*)d_ws;
  size_t off = 0;
  auto alloc = [&](size_t bytes) -> char* {
    char* p = ws + off;
    off += (bytes + 255) & ~(size_t)255;
    return p;
  };
  u16* x0bf = (u16*)alloc((size_t)MROWS * 256 * 2);
  u16* y1 = (u16*)alloc((size_t)MROWS * 512 * 2);
  u16* y2 = (u16*)alloc((size_t)MROWS * 512 * 2);
  // contiguous zero-init region: stats0 (512f) | stats1 (1024f) | stats2 (1024f) | maxbuf (32768u)
  float* s0sum = (float*)alloc((512 + 1024 + 1024 + 32768) * 4);
  float* s0sq = s0sum + 256;
  float* s1sum = s0sum + 512;
  float* s1sq = s1sum + 512;
  float* s2sum = s1sum + 1024;
  float* s2sq = s2sum + 512;
  unsigned* maxbuf = (unsigned*)(s0sum + 2560);
  const size_t zbytes = (size_t)(2560 + 32768) * 4;
  u16* W0p = (u16*)alloc(512 * 256 * 2);
  u16* W1p = (u16*)alloc(512 * 512 * 2);
  u16* W2p = (u16*)alloc(1024 * 512 * 2);
  float* c0p = (float*)alloc(512 * 4);
  float* c1p = (float*)alloc(512 * 4);
  float* c2p = (float*)alloc(1024 * 4);
  if (off > ws_size) return;  // workspace too small: bail loudly (validation will fail)

  hipMemsetAsync(s0sum, 0, zbytes, stream);

  // layer 0 (epilogue produces layer-1 BN stats)
  stats_cast_k<<<512, 256, 0, stream>>>(x0, x0bf, s0sum, s0sq);
  prep_w_k<<<512, 256, 0, stream>>>(W0, g0, b0, c0, s0sum, s0sq, W0p, c0p, 256);
  gemm_k<true, false><<<512 * 4, 256, 0, stream>>>(x0bf, W0p, c0p, y1, s1sum, s1sq, nullptr, 256, 512);
  // layer 1 (epilogue produces layer-2 BN stats)
  prep_w_k<<<512, 256, 0, stream>>>(W1, g1, b1, c1, s1sum, s1sq, W1p, c1p, 512);
  gemm_k<true, false><<<512 * 4, 256, 0, stream>>>(y1, W1p, c1p, y2, s2sum, s2sq, nullptr, 512, 512);
  // layer 2 + max reduction
  prep_w_k<<<1024, 256, 0, stream>>>(W2, g2, b2, c2, s2sum, s2sq, W2p, c2p, 512);
  gemm_k<false, true><<<512 * 8, 256, 0, stream>>>(y2, W2p, c2p, nullptr, nullptr, nullptr, maxbuf, 512, 1024);
  decode_k<<<128, 256, 0, stream>>>(maxbuf, (float*)d_out, 32768);
}

// Round 3
// 256.074 us; speedup vs baseline: 2.0667x; 1.0427x over previous
//
#include <hip/hip_runtime.h>
#include <hip/hip_bf16.h>
#include <stdint.h>

typedef unsigned short u16;
typedef __attribute__((ext_vector_type(8))) __bf16 bf16x8;
typedef __attribute__((ext_vector_type(4))) float f32x4;

#define BN_EPS 1e-5f
#define MROWS 65536
#define INV_M (1.0f / 65536.0f)

__device__ __forceinline__ u16 f2bf(float f) {
  unsigned u = __builtin_bit_cast(unsigned, f);
  unsigned r = (u + 0x7FFFu + ((u >> 16) & 1u)) >> 16;
  return (u16)r;
}
__device__ __forceinline__ float bf2f(u16 h) {
  return __builtin_bit_cast(float, (unsigned)h << 16);
}

// ------------- layer-0 stats + fp32->bf16 cast: x [65536,256] -------------
__global__ __launch_bounds__(256)
void stats_cast_k(const float* __restrict__ x, u16* __restrict__ xbf,
                  float* __restrict__ ssum, float* __restrict__ ssq) {
  const int t = threadIdx.x;
  const int tc = t & 63, tr = t >> 6;
  const int r0 = blockIdx.x * 128;
  float s0 = 0, s1 = 0, s2 = 0, s3 = 0, q0 = 0, q1 = 0, q2 = 0, q3 = 0;
  for (int r = r0 + tr; r < r0 + 128; r += 4) {
    float4 v = *(const float4*)(x + (size_t)r * 256 + tc * 4);
    ushort4 ov;
    ov.x = f2bf(v.x); ov.y = f2bf(v.y); ov.z = f2bf(v.z); ov.w = f2bf(v.w);
    *(ushort4*)(xbf + (size_t)r * 256 + tc * 4) = ov;
    s0 += v.x; q0 += v.x * v.x;
    s1 += v.y; q1 += v.y * v.y;
    s2 += v.z; q2 += v.z * v.z;
    s3 += v.w; q3 += v.w * v.w;
  }
  __shared__ float red[4][256];
  red[tr][tc * 4 + 0] = s0; red[tr][tc * 4 + 1] = s1;
  red[tr][tc * 4 + 2] = s2; red[tr][tc * 4 + 3] = s3;
  __syncthreads();
  if (tr == 0) {
#pragma unroll
    for (int i = 0; i < 4; ++i) {
      int c = tc * 4 + i;
      atomicAdd(&ssum[c], red[0][c] + red[1][c] + red[2][c] + red[3][c]);
    }
  }
  __syncthreads();
  red[tr][tc * 4 + 0] = q0; red[tr][tc * 4 + 1] = q1;
  red[tr][tc * 4 + 2] = q2; red[tr][tc * 4 + 3] = q3;
  __syncthreads();
  if (tr == 0) {
#pragma unroll
    for (int i = 0; i < 4; ++i) {
      int c = tc * 4 + i;
      atomicAdd(&ssq[c], red[0][c] + red[1][c] + red[2][c] + red[3][c]);
    }
  }
}

// ------------- fold BN into weights -------------
__global__ __launch_bounds__(256)
void prep_w_k(const float* __restrict__ W, const float* __restrict__ g,
              const float* __restrict__ b, const float* __restrict__ c,
              const float* __restrict__ ssum, const float* __restrict__ ssq,
              u16* __restrict__ Wp, float* __restrict__ cp, int din) {
  const int o = blockIdx.x, t = threadIdx.x;
  float acc = 0.f;
  for (int d = t; d < din; d += 256) {
    float mean = ssum[d] * INV_M;
    float var = ssq[d] * INV_M - mean * mean;
    float alpha = g[d] * rsqrtf(var + BN_EPS);
    float beta = b[d] - mean * alpha;
    float w = W[(size_t)o * din + d];
    Wp[(size_t)o * din + d] = f2bf(w * alpha);
    acc += w * beta;
  }
#pragma unroll
  for (int off = 32; off > 0; off >>= 1) acc += __shfl_down(acc, off, 64);
  __shared__ float wsum[4];
  if ((t & 63) == 0) wsum[t >> 6] = acc;
  __syncthreads();
  if (t == 0) cp[o] = c[o] + wsum[0] + wsum[1] + wsum[2] + wsum[3];
}

// ------------- GEMM: Y = act(A @ B^T + c'), 256x256 tile, BK=32, ring-4 LDS -------------
// 8 waves (2M x 4N), per-wave 128x64 output. Phase-interleaved counted-vmcnt schedule:
// staging runs 3 K-tiles ahead; boundary wait is vmcnt(8) (never 0 in steady state).
// LDS XOR-swizzle (row&3)<<4 on byte col, applied to global SOURCE (linear gload_lds
// dest) and to ds_read addresses (both-sides rule). Raw s_barrier only.
#define GLDS16(gp, lp) __builtin_amdgcn_global_load_lds( \
    (__attribute__((address_space(1))) void*)(void*)(gp), \
    (__attribute__((address_space(3))) void*)(lp), 16, 0, 0)

template <bool RELU, bool DOMAX>
__global__ __launch_bounds__(512, 2)
void gemm_k(const u16* __restrict__ A, const u16* __restrict__ B,
            const float* __restrict__ cp, u16* __restrict__ Y,
            float* __restrict__ osum, float* __restrict__ osq,
            unsigned* __restrict__ maxbuf, int K, int N) {
  // ring4: A slots [4][8192] u16, then B slots [4][8192] u16  => 128 KiB
  __shared__ __align__(16) u16 lds[8 * 8192];
  const int t = threadIdx.x;
  const int w = t >> 6, l = t & 63;
  const int lr = l & 15, lk = l >> 4;
  const int wm = w >> 2, wn = w & 3;

  // XCD-aware bijective swizzle (gridDim.x % 8 == 0 for all launches here)
  const int cpx = (int)gridDim.x >> 3;
  int bid = (int)blockIdx.x;
  bid = (bid & 7) * cpx + (bid >> 3);
  const int tiles_n = N >> 8;
  const int tm0 = (bid / tiles_n) << 8;
  const int tn0 = (bid % tiles_n) << 8;

  // staging geometry: matrix tile = 256 rows x 32 cols u16 (16 KB), 1024 16B segs,
  // thread t owns segs t and t+512. Physical seg t: row t/4, colbyte (t&3)*16.
  // Global source col pre-swizzled: colbyte ^ ((row&3)<<4).
  const int srow = t >> 2;
  const int scol = (((t & 3) << 4) ^ ((srow & 3) << 4)) >> 1;  // u16 units
  const u16* Ag = A + (size_t)(tm0 + srow) * K + scol;
  const u16* Bg = B + (size_t)(tn0 + srow) * K + scol;
  u16* const ldsA = lds;
  u16* const ldsB = lds + 4 * 8192;

#define STAGE_A(slot_, kt_) do { \
    GLDS16(Ag + (kt_) * 32, ldsA + (slot_) * 8192 + t * 8); \
    GLDS16(Ag + (size_t)128 * K + (kt_) * 32, ldsA + (slot_) * 8192 + 4096 + t * 8); \
  } while (0)
#define STAGE_B(slot_, kt_) do { \
    GLDS16(Bg + (kt_) * 32, ldsB + (slot_) * 8192 + t * 8); \
    GLDS16(Bg + (size_t)128 * K + (kt_) * 32, ldsB + (slot_) * 8192 + 4096 + t * 8); \
  } while (0)

  // ds_read addressing: lane reads row (base + frag*16 + lr), k-bytes lk*16,
  // swizzled: pc u16 = ((lk ^ (lr&3)) * 8)
  const int pc = (lk ^ (lr & 3)) * 8;
  const int rba = wm * 128 + lr;  // A row base
  const int rbb = wn * 64 + lr;   // B row base

  f32x4 acc[8][4] = {};
  const int nk = K >> 5;  // K-tiles (nk >= 8 for all layers)

  // prologue: stage tiles 0,1,2 (lead = 3)
  STAGE_A(0, 0); STAGE_B(0, 0);
  STAGE_A(1, 1); STAGE_B(1, 1);
  STAGE_A(2, 2); STAGE_B(2, 2);
  asm volatile("s_waitcnt vmcnt(8)" ::: "memory");  // tile 0 landed
  __builtin_amdgcn_s_barrier();

  for (int T = 0; T < nk; ++T) {
    const int sl = T & 3;
    const u16* la = ldsA + sl * 8192;
    const u16* lb = ldsB + sl * 8192;
    bf16x8 af[4], bf[4];
    // ---- phase 0: B frags (all 4) + A frags m=0..3 ----
#pragma unroll
    for (int n = 0; n < 4; ++n)
      bf[n] = *(const bf16x8*)(lb + (rbb + n * 16) * 32 + pc);
#pragma unroll
    for (int j = 0; j < 4; ++j)
      af[j] = *(const bf16x8*)(la + (rba + j * 16) * 32 + pc);
    if (T + 3 < nk) STAGE_A((T + 3) & 3, T + 3);
    __builtin_amdgcn_s_barrier();
    __builtin_amdgcn_s_setprio(1);
#pragma unroll
    for (int j = 0; j < 4; ++j)
#pragma unroll
      for (int n = 0; n < 4; ++n)
        acc[j][n] = __builtin_amdgcn_mfma_f32_16x16x32_bf16(af[j], bf[n], acc[j][n], 0, 0, 0);
    __builtin_amdgcn_s_setprio(0);
    // ---- phase 1: A frags m=4..7 (B reused in regs) ----
#pragma unroll
    for (int j = 0; j < 4; ++j)
      af[j] = *(const bf16x8*)(la + (rba + 64 + j * 16) * 32 + pc);
    if (T + 3 < nk) STAGE_B((T + 3) & 3, T + 3);
    // K-tile boundary wait: next tile's data must be landed for ALL waves
    // before the barrier releases them into its reads. Counted, never 0 mid-loop.
    if (T < nk - 3)       asm volatile("s_waitcnt vmcnt(8)" ::: "memory");
    else if (T == nk - 3) asm volatile("s_waitcnt vmcnt(4)" ::: "memory");
    else if (T == nk - 2) asm volatile("s_waitcnt vmcnt(0)" ::: "memory");
    __builtin_amdgcn_s_barrier();
    __builtin_amdgcn_s_setprio(1);
#pragma unroll
    for (int j = 0; j < 4; ++j)
#pragma unroll
      for (int n = 0; n < 4; ++n)
        acc[4 + j][n] = __builtin_amdgcn_mfma_f32_16x16x32_bf16(af[j], bf[n], acc[4 + j][n], 0, 0, 0);
    __builtin_amdgcn_s_setprio(0);
  }

  if (!DOMAX) {
    float cs[4] = {}, cq[4] = {};
#pragma unroll
    for (int n = 0; n < 4; ++n) {
      const int gcol = tn0 + wn * 64 + n * 16 + lr;
      const float cb = cp[gcol];
#pragma unroll
      for (int m = 0; m < 8; ++m) {
        const int grow = tm0 + wm * 128 + m * 16 + lk * 4;
#pragma unroll
        for (int r = 0; r < 4; ++r) {
          float v = acc[m][n][r] + cb;
          if (RELU) v = fmaxf(v, 0.f);
          Y[(size_t)(grow + r) * N + gcol] = f2bf(v);
          cs[n] += v;
          cq[n] += v * v;
        }
      }
    }
    if (RELU) {
#pragma unroll
      for (int n = 0; n < 4; ++n) {
        cs[n] += __shfl_xor(cs[n], 16, 64);
        cs[n] += __shfl_xor(cs[n], 32, 64);
        cq[n] += __shfl_xor(cq[n], 16, 64);
        cq[n] += __shfl_xor(cq[n], 32, 64);
      }
      float* sred = (float*)lds;  // [wm][256] sum | +512: [wm][256] sq
      __syncthreads();
      if (lk == 0) {
#pragma unroll
        for (int n = 0; n < 4; ++n) {
          const int c = wn * 64 + n * 16 + lr;
          sred[wm * 256 + c] = cs[n];
          sred[512 + wm * 256 + c] = cq[n];
        }
      }
      __syncthreads();
      if (t < 256) {
        atomicAdd(&osum[tn0 + t], sred[t] + sred[256 + t]);
      } else {
        const int c = t - 256;
        atomicAdd(&osq[tn0 + c], sred[512 + c] + sred[768 + c]);
      }
    }
  } else {
    // max-over-set epilogue: tile fully inside one batch (2048 % 256 == 0)
    const int batch = tm0 >> 11;
#pragma unroll
    for (int n = 0; n < 4; ++n) {
      const int gcol = tn0 + wn * 64 + n * 16 + lr;
      const float cb = cp[gcol];
      float mx = -3.0e38f;
#pragma unroll
      for (int m = 0; m < 8; ++m)
#pragma unroll
        for (int r = 0; r < 4; ++r)
          mx = fmaxf(mx, acc[m][n][r] + cb);
      mx = fmaxf(mx, __shfl_xor(mx, 16, 64));
      mx = fmaxf(mx, __shfl_xor(mx, 32, 64));
      if (lk == 0) {
        unsigned u = __builtin_bit_cast(unsigned, mx);
        u = (u & 0x80000000u) ? ~u : (u | 0x80000000u);
        atomicMax(&maxbuf[batch * N + gcol], u);
      }
    }
  }
#undef STAGE_A
#undef STAGE_B
}

__global__ void decode_k(const unsigned* __restrict__ mb, float* __restrict__ out, int n) {
  int i = blockIdx.x * 256 + threadIdx.x;
  if (i < n) {
    unsigned u = mb[i];
    u = (u & 0x80000000u) ? (u & 0x7FFFFFFFu) : ~u;
    out[i] = __builtin_bit_cast(float, u);
  }
}

extern "C" void kernel_launch(void* const* d_in, const int* in_sizes, int n_in,
                              void* d_out, int out_size, void* d_ws, size_t ws_size,
                              hipStream_t stream) {
  const float* x0 = (const float*)d_in[0];
  const float* g0 = (const float*)d_in[1];
  const float* b0 = (const float*)d_in[2];
  const float* W0 = (const float*)d_in[3];
  const float* c0 = (const float*)d_in[4];
  const float* g1 = (const float*)d_in[5];
  const float* b1 = (const float*)d_in[6];
  const float* W1 = (const float*)d_in[7];
  const float* c1 = (const float*)d_in[8];
  const float* g2 = (const float*)d_in[9];
  const float* b2 = (const float*)d_in[10];
  const float* W2 = (const float*)d_in[11];
  const float* c2 = (const float*)d_in[12];

  char* ws = (char*)d_ws;
  size_t off = 0;
  auto alloc = [&](size_t bytes) -> char* {
    char* p = ws + off;
    off += (bytes + 255) & ~(size_t)255;
    return p;
  };
  u16* x0bf = (u16*)alloc((size_t)MROWS * 256 * 2);
  u16* y1 = (u16*)alloc((size_t)MROWS * 512 * 2);
  u16* y2 = (u16*)alloc((size_t)MROWS * 512 * 2);
  // contiguous zero-init region: stats0 | stats1 | stats2 | maxbuf
  float* s0sum = (float*)alloc((512 + 1024 + 1024 + 32768) * 4);
  float* s0sq = s0sum + 256;
  float* s1sum = s0sum + 512;
  float* s1sq = s1sum + 512;
  float* s2sum = s1sum + 1024;
  float* s2sq = s2sum + 512;
  unsigned* maxbuf = (unsigned*)(s0sum + 2560);
  const size_t zbytes = (size_t)(2560 + 32768) * 4;
  u16* W0p = (u16*)alloc(512 * 256 * 2);
  u16* W1p = (u16*)alloc(512 * 512 * 2);
  u16* W2p = (u16*)alloc(1024 * 512 * 2);
  float* c0p = (float*)alloc(512 * 4);
  float* c1p = (float*)alloc(512 * 4);
  float* c2p = (float*)alloc(1024 * 4);
  if (off > ws_size) return;

  hipMemsetAsync(s0sum, 0, zbytes, stream);

  // layer 0 (epilogue produces layer-1 BN stats)
  stats_cast_k<<<512, 256, 0, stream>>>(x0, x0bf, s0sum, s0sq);
  prep_w_k<<<512, 256, 0, stream>>>(W0, g0, b0, c0, s0sum, s0sq, W0p, c0p, 256);
  gemm_k<true, false><<<512, 512, 0, stream>>>(x0bf, W0p, c0p, y1, s1sum, s1sq, nullptr, 256, 512);
  // layer 1 (epilogue produces layer-2 BN stats)
  prep_w_k<<<512, 256, 0, stream>>>(W1, g1, b1, c1, s1sum, s1sq, W1p, c1p, 512);
  gemm_k<true, false><<<512, 512, 0, stream>>>(y1, W1p, c1p, y2, s2sum, s2sq, nullptr, 512, 512);
  // layer 2 + max reduction
  prep_w_k<<<1024, 256, 0, stream>>>(W2, g2, b2, c2, s2sum, s2sq, W2p, c2p, 512);
  gemm_k<false, true><<<1024, 512, 0, stream>>>(y2, W2p, c2p, nullptr, nullptr, nullptr, maxbuf, 512, 1024);
  decode_k<<<128, 256, 0, stream>>>(maxbuf, (float*)d_out, 32768);
}

// Round 4
// 252.313 us; speedup vs baseline: 2.0975x; 1.0149x over previous
//
#include <hip/hip_runtime.h>
#include <hip/hip_bf16.h>
#include <stdint.h>

typedef unsigned short u16;
typedef __attribute__((ext_vector_type(8))) __bf16 bf16x8;
typedef __attribute__((ext_vector_type(4))) float f32x4;

#define BN_EPS 1e-5f
#define MROWS 65536
#define INV_M (1.0f / 65536.0f)

__device__ __forceinline__ u16 f2bf(float f) {
  unsigned u = __builtin_bit_cast(unsigned, f);
  unsigned r = (u + 0x7FFFu + ((u >> 16) & 1u)) >> 16;
  return (u16)r;
}
__device__ __forceinline__ float bf2f(u16 h) {
  return __builtin_bit_cast(float, (unsigned)h << 16);
}

// ------------- layer-0 stats + fp32->bf16 cast: x [65536,256] -------------
// 512 blocks x 256 thr; block owns 128 rows. 8-deep load batching for MLP
// (round-3 profile: 78us, VALUBusy 2.4% -> latency-bound at 1-deep).
__global__ __launch_bounds__(256)
void stats_cast_k(const float* __restrict__ x, u16* __restrict__ xbf,
                  float* __restrict__ ssum, float* __restrict__ ssq) {
  const int t = threadIdx.x;
  const int tc = t & 63, tr = t >> 6;
  const int r0 = blockIdx.x * 128;
  float s0 = 0, s1 = 0, s2 = 0, s3 = 0, q0 = 0, q1 = 0, q2 = 0, q3 = 0;
#pragma unroll
  for (int it = 0; it < 4; ++it) {
    const int rb = r0 + tr + it * 32;
    float4 v[8];
#pragma unroll
    for (int i = 0; i < 8; ++i)
      v[i] = *(const float4*)(x + (size_t)(rb + i * 4) * 256 + tc * 4);
#pragma unroll
    for (int i = 0; i < 8; ++i) {
      ushort4 ov;
      ov.x = f2bf(v[i].x); ov.y = f2bf(v[i].y);
      ov.z = f2bf(v[i].z); ov.w = f2bf(v[i].w);
      *(ushort4*)(xbf + (size_t)(rb + i * 4) * 256 + tc * 4) = ov;
      s0 += v[i].x; q0 += v[i].x * v[i].x;
      s1 += v[i].y; q1 += v[i].y * v[i].y;
      s2 += v[i].z; q2 += v[i].z * v[i].z;
      s3 += v[i].w; q3 += v[i].w * v[i].w;
    }
  }
  __shared__ float red[4][256];
  red[tr][tc * 4 + 0] = s0; red[tr][tc * 4 + 1] = s1;
  red[tr][tc * 4 + 2] = s2; red[tr][tc * 4 + 3] = s3;
  __syncthreads();
  if (tr == 0) {
#pragma unroll
    for (int i = 0; i < 4; ++i) {
      int c = tc * 4 + i;
      atomicAdd(&ssum[c], red[0][c] + red[1][c] + red[2][c] + red[3][c]);
    }
  }
  __syncthreads();
  red[tr][tc * 4 + 0] = q0; red[tr][tc * 4 + 1] = q1;
  red[tr][tc * 4 + 2] = q2; red[tr][tc * 4 + 3] = q3;
  __syncthreads();
  if (tr == 0) {
#pragma unroll
    for (int i = 0; i < 4; ++i) {
      int c = tc * 4 + i;
      atomicAdd(&ssq[c], red[0][c] + red[1][c] + red[2][c] + red[3][c]);
    }
  }
}

// ------------- fold BN into weights: one WAVE per output row, float4 loads -------------
__global__ __launch_bounds__(256)
void prep_w_k(const float* __restrict__ W, const float* __restrict__ g,
              const float* __restrict__ b, const float* __restrict__ c,
              const float* __restrict__ ssum, const float* __restrict__ ssq,
              u16* __restrict__ Wp, float* __restrict__ cp, int din, int dout) {
  const int gw = (blockIdx.x * 256 + threadIdx.x) >> 6;  // global wave = row
  const int l = threadIdx.x & 63;
  if (gw >= dout) return;
  const int o = gw;
  float acc = 0.f;
  for (int d0 = l * 4; d0 < din; d0 += 256) {
    float4 wv = *(const float4*)(W + (size_t)o * din + d0);
    float4 sm = *(const float4*)(ssum + d0);
    float4 sq = *(const float4*)(ssq + d0);
    float4 gv = *(const float4*)(g + d0);
    float4 bv = *(const float4*)(b + d0);
    float w4[4] = {wv.x, wv.y, wv.z, wv.w};
    float m4[4] = {sm.x, sm.y, sm.z, sm.w};
    float q4[4] = {sq.x, sq.y, sq.z, sq.w};
    float g4[4] = {gv.x, gv.y, gv.z, gv.w};
    float b4[4] = {bv.x, bv.y, bv.z, bv.w};
    ushort4 ov;
    u16 o4[4];
#pragma unroll
    for (int i = 0; i < 4; ++i) {
      float mean = m4[i] * INV_M;
      float var = q4[i] * INV_M - mean * mean;
      float alpha = g4[i] * rsqrtf(var + BN_EPS);
      float beta = b4[i] - mean * alpha;
      o4[i] = f2bf(w4[i] * alpha);
      acc += w4[i] * beta;
    }
    ov.x = o4[0]; ov.y = o4[1]; ov.z = o4[2]; ov.w = o4[3];
    *(ushort4*)(Wp + (size_t)o * din + d0) = ov;
  }
#pragma unroll
  for (int off = 32; off > 0; off >>= 1) acc += __shfl_xor(acc, off, 64);
  if (l == 0) cp[o] = c[o] + acc;
}

// ------------- GEMM: Y = act(A @ B^T + c'), 256x256 tile, BK=32, ring-4 LDS -------------
// 8 waves (2M x 4N), per-wave 128x64 output. Phase-interleaved counted-vmcnt schedule:
// staging runs 3 K-tiles ahead; boundary wait is vmcnt(8) (never 0 in steady state).
// LDS XOR-swizzle (row&3)<<4 on byte col, applied to global SOURCE (linear gload_lds
// dest) and to ds_read addresses (both-sides rule). Raw s_barrier only.
#define GLDS16(gp, lp) __builtin_amdgcn_global_load_lds( \
    (__attribute__((address_space(1))) void*)(void*)(gp), \
    (__attribute__((address_space(3))) void*)(lp), 16, 0, 0)

template <bool RELU, bool DOMAX>
__global__ __launch_bounds__(512, 2)
void gemm_k(const u16* __restrict__ A, const u16* __restrict__ B,
            const float* __restrict__ cp, u16* __restrict__ Y,
            float* __restrict__ osum, float* __restrict__ osq,
            unsigned* __restrict__ maxbuf, int K, int N) {
  // ring4: A slots [4][8192] u16, then B slots [4][8192] u16  => 128 KiB
  __shared__ __align__(16) u16 lds[8 * 8192];
  const int t = threadIdx.x;
  const int w = t >> 6, l = t & 63;
  const int lr = l & 15, lk = l >> 4;
  const int wm = w >> 2, wn = w & 3;

  // XCD-aware bijective swizzle (gridDim.x % 8 == 0 for all launches here)
  const int cpx = (int)gridDim.x >> 3;
  int bid = (int)blockIdx.x;
  bid = (bid & 7) * cpx + (bid >> 3);
  const int tiles_n = N >> 8;
  const int tm0 = (bid / tiles_n) << 8;
  const int tn0 = (bid % tiles_n) << 8;

  // staging geometry: matrix tile = 256 rows x 32 cols u16 (16 KB), 1024 16B segs,
  // thread t owns segs t and t+512. Physical seg t: row t/4, colbyte (t&3)*16.
  // Global source col pre-swizzled: colbyte ^ ((row&3)<<4).
  const int srow = t >> 2;
  const int scol = (((t & 3) << 4) ^ ((srow & 3) << 4)) >> 1;  // u16 units
  const u16* Ag = A + (size_t)(tm0 + srow) * K + scol;
  const u16* Bg = B + (size_t)(tn0 + srow) * K + scol;
  u16* const ldsA = lds;
  u16* const ldsB = lds + 4 * 8192;

#define STAGE_A(slot_, kt_) do { \
    GLDS16(Ag + (kt_) * 32, ldsA + (slot_) * 8192 + t * 8); \
    GLDS16(Ag + (size_t)128 * K + (kt_) * 32, ldsA + (slot_) * 8192 + 4096 + t * 8); \
  } while (0)
#define STAGE_B(slot_, kt_) do { \
    GLDS16(Bg + (kt_) * 32, ldsB + (slot_) * 8192 + t * 8); \
    GLDS16(Bg + (size_t)128 * K + (kt_) * 32, ldsB + (slot_) * 8192 + 4096 + t * 8); \
  } while (0)

  // ds_read addressing: lane reads row (base + frag*16 + lr), k-bytes lk*16,
  // swizzled: pc u16 = ((lk ^ (lr&3)) * 8)
  const int pc = (lk ^ (lr & 3)) * 8;
  const int rba = wm * 128 + lr;  // A row base
  const int rbb = wn * 64 + lr;   // B row base

  f32x4 acc[8][4] = {};
  const int nk = K >> 5;  // K-tiles (nk >= 8 for all layers)

  // prologue: stage tiles 0,1,2 (lead = 3)
  STAGE_A(0, 0); STAGE_B(0, 0);
  STAGE_A(1, 1); STAGE_B(1, 1);
  STAGE_A(2, 2); STAGE_B(2, 2);
  asm volatile("s_waitcnt vmcnt(8)" ::: "memory");  // tile 0 landed
  __builtin_amdgcn_s_barrier();

  for (int T = 0; T < nk; ++T) {
    const int sl = T & 3;
    const u16* la = ldsA + sl * 8192;
    const u16* lb = ldsB + sl * 8192;
    bf16x8 af[4], bf[4];
    // ---- phase 0: B frags (all 4) + A frags m=0..3 ----
#pragma unroll
    for (int n = 0; n < 4; ++n)
      bf[n] = *(const bf16x8*)(lb + (rbb + n * 16) * 32 + pc);
#pragma unroll
    for (int j = 0; j < 4; ++j)
      af[j] = *(const bf16x8*)(la + (rba + j * 16) * 32 + pc);
    if (T + 3 < nk) STAGE_A((T + 3) & 3, T + 3);
    __builtin_amdgcn_s_barrier();
    __builtin_amdgcn_s_setprio(1);
#pragma unroll
    for (int j = 0; j < 4; ++j)
#pragma unroll
      for (int n = 0; n < 4; ++n)
        acc[j][n] = __builtin_amdgcn_mfma_f32_16x16x32_bf16(af[j], bf[n], acc[j][n], 0, 0, 0);
    __builtin_amdgcn_s_setprio(0);
    // ---- phase 1: A frags m=4..7 (B reused in regs) ----
#pragma unroll
    for (int j = 0; j < 4; ++j)
      af[j] = *(const bf16x8*)(la + (rba + 64 + j * 16) * 32 + pc);
    if (T + 3 < nk) STAGE_B((T + 3) & 3, T + 3);
    // K-tile boundary wait: next tile's data must be landed for ALL waves
    // before the barrier releases them into its reads. Counted, never 0 mid-loop.
    if (T < nk - 3)       asm volatile("s_waitcnt vmcnt(8)" ::: "memory");
    else if (T == nk - 3) asm volatile("s_waitcnt vmcnt(4)" ::: "memory");
    else if (T == nk - 2) asm volatile("s_waitcnt vmcnt(0)" ::: "memory");
    __builtin_amdgcn_s_barrier();
    __builtin_amdgcn_s_setprio(1);
#pragma unroll
    for (int j = 0; j < 4; ++j)
#pragma unroll
      for (int n = 0; n < 4; ++n)
        acc[4 + j][n] = __builtin_amdgcn_mfma_f32_16x16x32_bf16(af[j], bf[n], acc[4 + j][n], 0, 0, 0);
    __builtin_amdgcn_s_setprio(0);
  }

  if (!DOMAX) {
    float cs[4] = {}, cq[4] = {};
#pragma unroll
    for (int n = 0; n < 4; ++n) {
      const int gcol = tn0 + wn * 64 + n * 16 + lr;
      const float cb = cp[gcol];
#pragma unroll
      for (int m = 0; m < 8; ++m) {
        const int grow = tm0 + wm * 128 + m * 16 + lk * 4;
#pragma unroll
        for (int r = 0; r < 4; ++r) {
          float v = acc[m][n][r] + cb;
          if (RELU) v = fmaxf(v, 0.f);
          Y[(size_t)(grow + r) * N + gcol] = f2bf(v);
          cs[n] += v;
          cq[n] += v * v;
        }
      }
    }
    if (RELU) {
#pragma unroll
      for (int n = 0; n < 4; ++n) {
        cs[n] += __shfl_xor(cs[n], 16, 64);
        cs[n] += __shfl_xor(cs[n], 32, 64);
        cq[n] += __shfl_xor(cq[n], 16, 64);
        cq[n] += __shfl_xor(cq[n], 32, 64);
      }
      float* sred = (float*)lds;  // [wm][256] sum | +512: [wm][256] sq
      __syncthreads();
      if (lk == 0) {
#pragma unroll
        for (int n = 0; n < 4; ++n) {
          const int c = wn * 64 + n * 16 + lr;
          sred[wm * 256 + c] = cs[n];
          sred[512 + wm * 256 + c] = cq[n];
        }
      }
      __syncthreads();
      if (t < 256) {
        atomicAdd(&osum[tn0 + t], sred[t] + sred[256 + t]);
      } else {
        const int c = t - 256;
        atomicAdd(&osq[tn0 + c], sred[512 + c] + sred[768 + c]);
      }
    }
  } else {
    // max-over-set epilogue: tile fully inside one batch (2048 % 256 == 0)
    const int batch = tm0 >> 11;
#pragma unroll
    for (int n = 0; n < 4; ++n) {
      const int gcol = tn0 + wn * 64 + n * 16 + lr;
      const float cb = cp[gcol];
      float mx = -3.0e38f;
#pragma unroll
      for (int m = 0; m < 8; ++m)
#pragma unroll
        for (int r = 0; r < 4; ++r)
          mx = fmaxf(mx, acc[m][n][r] + cb);
      mx = fmaxf(mx, __shfl_xor(mx, 16, 64));
      mx = fmaxf(mx, __shfl_xor(mx, 32, 64));
      if (lk == 0) {
        unsigned u = __builtin_bit_cast(unsigned, mx);
        u = (u & 0x80000000u) ? ~u : (u | 0x80000000u);
        atomicMax(&maxbuf[batch * N + gcol], u);
      }
    }
  }
#undef STAGE_A
#undef STAGE_B
}

__global__ void decode_k(const unsigned* __restrict__ mb, float* __restrict__ out, int n) {
  int i = blockIdx.x * 256 + threadIdx.x;
  if (i < n) {
    unsigned u = mb[i];
    u = (u & 0x80000000u) ? (u & 0x7FFFFFFFu) : ~u;
    out[i] = __builtin_bit_cast(float, u);
  }
}

extern "C" void kernel_launch(void* const* d_in, const int* in_sizes, int n_in,
                              void* d_out, int out_size, void* d_ws, size_t ws_size,
                              hipStream_t stream) {
  const float* x0 = (const float*)d_in[0];
  const float* g0 = (const float*)d_in[1];
  const float* b0 = (const float*)d_in[2];
  const float* W0 = (const float*)d_in[3];
  const float* c0 = (const float*)d_in[4];
  const float* g1 = (const float*)d_in[5];
  const float* b1 = (const float*)d_in[6];
  const float* W1 = (const float*)d_in[7];
  const float* c1 = (const float*)d_in[8];
  const float* g2 = (const float*)d_in[9];
  const float* b2 = (const float*)d_in[10];
  const float* W2 = (const float*)d_in[11];
  const float* c2 = (const float*)d_in[12];

  char* ws = (char*)d_ws;
  size_t off = 0;
  auto alloc = [&](size_t bytes) -> char* {
    char* p = ws + off;
    off += (bytes + 255) & ~(size_t)255;
    return p;
  };
  u16* x0bf = (u16*)alloc((size_t)MROWS * 256 * 2);
  u16* y1 = (u16*)alloc((size_t)MROWS * 512 * 2);
  u16* y2 = (u16*)alloc((size_t)MROWS * 512 * 2);
  // contiguous zero-init region: stats0 | stats1 | stats2 | maxbuf
  float* s0sum = (float*)alloc((512 + 1024 + 1024 + 32768) * 4);
  float* s0sq = s0sum + 256;
  float* s1sum = s0sum + 512;
  float* s1sq = s1sum + 512;
  float* s2sum = s1sum + 1024;
  float* s2sq = s2sum + 512;
  unsigned* maxbuf = (unsigned*)(s0sum + 2560);
  const size_t zbytes = (size_t)(2560 + 32768) * 4;
  u16* W0p = (u16*)alloc(512 * 256 * 2);
  u16* W1p = (u16*)alloc(512 * 512 * 2);
  u16* W2p = (u16*)alloc(1024 * 512 * 2);
  float* c0p = (float*)alloc(512 * 4);
  float* c1p = (float*)alloc(512 * 4);
  float* c2p = (float*)alloc(1024 * 4);
  if (off > ws_size) return;

  hipMemsetAsync(s0sum, 0, zbytes, stream);

  // layer 0 (epilogue produces layer-1 BN stats)
  stats_cast_k<<<512, 256, 0, stream>>>(x0, x0bf, s0sum, s0sq);
  prep_w_k<<<128, 256, 0, stream>>>(W0, g0, b0, c0, s0sum, s0sq, W0p, c0p, 256, 512);
  gemm_k<true, false><<<512, 512, 0, stream>>>(x0bf, W0p, c0p, y1, s1sum, s1sq, nullptr, 256, 512);
  // layer 1 (epilogue produces layer-2 BN stats)
  prep_w_k<<<128, 256, 0, stream>>>(W1, g1, b1, c1, s1sum, s1sq, W1p, c1p, 512, 512);
  gemm_k<true, false><<<512, 512, 0, stream>>>(y1, W1p, c1p, y2, s2sum, s2sq, nullptr, 512, 512);
  // layer 2 + max reduction
  prep_w_k<<<256, 256, 0, stream>>>(W2, g2, b2, c2, s2sum, s2sq, W2p, c2p, 512, 1024);
  gemm_k<false, true><<<1024, 512, 0, stream>>>(y2, W2p, c2p, nullptr, nullptr, nullptr, maxbuf, 512, 1024);
  decode_k<<<128, 256, 0, stream>>>(maxbuf, (float*)d_out, 32768);
}

// Round 5
// 211.899 us; speedup vs baseline: 2.4975x; 1.1907x over previous
//
#include <hip/hip_runtime.h>
#include <hip/hip_bf16.h>
#include <stdint.h>

typedef unsigned short u16;
typedef __attribute__((ext_vector_type(8))) __bf16 bf16x8;
typedef __attribute__((ext_vector_type(4))) float f32x4;

#define BN_EPS 1e-5f
#define MROWS 65536
#define INV_M (1.0f / 65536.0f)
#define NREP 16  // stat-buffer replication for atomic decontention

__device__ __forceinline__ u16 f2bf(float f) {
  unsigned u = __builtin_bit_cast(unsigned, f);
  unsigned r = (u + 0x7FFFu + ((u >> 16) & 1u)) >> 16;
  return (u16)r;
}
__device__ __forceinline__ float bf2f(u16 h) {
  return __builtin_bit_cast(float, (unsigned)h << 16);
}

// ------------- layer-0 stats + fp32->bf16 cast: x [65536,256] -------------
// 2048 blocks x 256 thr (32 waves/CU); each block 32 rows; 8 float4 loads
// in flight per thread (latency-bound fix, r3: VALUBusy 2.4% at 1-deep).
// Stats atomically added into replica blockIdx&15 (chain 2048 -> 128/addr).
__global__ __launch_bounds__(256)
void stats_cast_k(const float* __restrict__ x, u16* __restrict__ xbf,
                  float* __restrict__ srep /* [NREP][512]: sum|sq */) {
  const int t = threadIdx.x;
  const int tc = t & 63, tr = t >> 6;
  const int rb = blockIdx.x * 32 + tr * 8;
  float4 v[8];
#pragma unroll
  for (int i = 0; i < 8; ++i)
    v[i] = *(const float4*)(x + (size_t)(rb + i) * 256 + tc * 4);
  float s0 = 0, s1 = 0, s2 = 0, s3 = 0, q0 = 0, q1 = 0, q2 = 0, q3 = 0;
#pragma unroll
  for (int i = 0; i < 8; ++i) {
    ushort4 ov;
    ov.x = f2bf(v[i].x); ov.y = f2bf(v[i].y);
    ov.z = f2bf(v[i].z); ov.w = f2bf(v[i].w);
    *(ushort4*)(xbf + (size_t)(rb + i) * 256 + tc * 4) = ov;
    s0 += v[i].x; q0 += v[i].x * v[i].x;
    s1 += v[i].y; q1 += v[i].y * v[i].y;
    s2 += v[i].z; q2 += v[i].z * v[i].z;
    s3 += v[i].w; q3 += v[i].w * v[i].w;
  }
  __shared__ float red[4][256];
  red[tr][tc * 4 + 0] = s0; red[tr][tc * 4 + 1] = s1;
  red[tr][tc * 4 + 2] = s2; red[tr][tc * 4 + 3] = s3;
  __syncthreads();
  float* dst = srep + (blockIdx.x & (NREP - 1)) * 512;
  if (tr == 0) {
#pragma unroll
    for (int i = 0; i < 4; ++i) {
      int c = tc * 4 + i;
      atomicAdd(&dst[c], red[0][c] + red[1][c] + red[2][c] + red[3][c]);
    }
  }
  __syncthreads();
  red[tr][tc * 4 + 0] = q0; red[tr][tc * 4 + 1] = q1;
  red[tr][tc * 4 + 2] = q2; red[tr][tc * 4 + 3] = q3;
  __syncthreads();
  if (tr == 0) {
#pragma unroll
    for (int i = 0; i < 4; ++i) {
      int c = tc * 4 + i;
      atomicAdd(&dst[256 + c], red[0][c] + red[1][c] + red[2][c] + red[3][c]);
    }
  }
}

// ------------- fold BN into weights: one WAVE per output row, float4 loads -------------
// Stats may be replicated: mean = (sum over nrep replicas) / M.
__global__ __launch_bounds__(256)
void prep_w_k(const float* __restrict__ W, const float* __restrict__ g,
              const float* __restrict__ b, const float* __restrict__ c,
              const float* __restrict__ ssum, const float* __restrict__ ssq,
              int rep_stride, int nrep,
              u16* __restrict__ Wp, float* __restrict__ cp, int din, int dout) {
  const int gw = (blockIdx.x * 256 + threadIdx.x) >> 6;  // global wave = row
  const int l = threadIdx.x & 63;
  if (gw >= dout) return;
  const int o = gw;
  float acc = 0.f;
  for (int d0 = l * 4; d0 < din; d0 += 256) {
    float sm[4] = {}, sq[4] = {};
    for (int r = 0; r < nrep; ++r) {
      float4 a = *(const float4*)(ssum + (size_t)r * rep_stride + d0);
      float4 z = *(const float4*)(ssq + (size_t)r * rep_stride + d0);
      sm[0] += a.x; sm[1] += a.y; sm[2] += a.z; sm[3] += a.w;
      sq[0] += z.x; sq[1] += z.y; sq[2] += z.z; sq[3] += z.w;
    }
    float4 wv = *(const float4*)(W + (size_t)o * din + d0);
    float4 gv = *(const float4*)(g + d0);
    float4 bv = *(const float4*)(b + d0);
    float w4[4] = {wv.x, wv.y, wv.z, wv.w};
    float g4[4] = {gv.x, gv.y, gv.z, gv.w};
    float b4[4] = {bv.x, bv.y, bv.z, bv.w};
    ushort4 ov;
    u16 o4[4];
#pragma unroll
    for (int i = 0; i < 4; ++i) {
      float mean = sm[i] * INV_M;
      float var = sq[i] * INV_M - mean * mean;
      float alpha = g4[i] * rsqrtf(var + BN_EPS);
      float beta = b4[i] - mean * alpha;
      o4[i] = f2bf(w4[i] * alpha);
      acc += w4[i] * beta;
    }
    ov.x = o4[0]; ov.y = o4[1]; ov.z = o4[2]; ov.w = o4[3];
    *(ushort4*)(Wp + (size_t)o * din + d0) = ov;
  }
#pragma unroll
  for (int off = 32; off > 0; off >>= 1) acc += __shfl_xor(acc, off, 64);
  if (l == 0) cp[o] = c[o] + acc;
}

// ------------- GEMM: Y = act(A @ B^T + c'), 256x256 tile, BK=32, ring-4 LDS -------------
// 8 waves (2M x 4N), per-wave 128x64 output. Counted-vmcnt schedule, lead 3 K-tiles,
// boundary wait vmcnt(8) (never 0 mid-loop). LDS swizzle: slot ^= (row>>1)&3
// (r4 fix: (row&3) left a 4-way conflict; (row>>1)&3 makes each 16-lane quad-phase
// cover all 8 16B-chunk positions -> 2-way = free). Applied to global SOURCE
// (linear gload_lds dest) and ds_read addresses.
#define GLDS16(gp, lp) __builtin_amdgcn_global_load_lds( \
    (__attribute__((address_space(1))) void*)(void*)(gp), \
    (__attribute__((address_space(3))) void*)(lp), 16, 0, 0)

template <bool RELU, bool DOMAX>
__global__ __launch_bounds__(512, 2)
void gemm_k(const u16* __restrict__ A, const u16* __restrict__ B,
            const float* __restrict__ cp, u16* __restrict__ Y,
            float* __restrict__ osum, float* __restrict__ osq,
            unsigned* __restrict__ maxbuf, int K, int N) {
  // ring4: A slots [4][8192] u16, then B slots [4][8192] u16  => 128 KiB
  __shared__ __align__(16) u16 lds[8 * 8192];
  const int t = threadIdx.x;
  const int w = t >> 6, l = t & 63;
  const int lr = l & 15, lk = l >> 4;
  const int wm = w >> 2, wn = w & 3;

  // XCD-aware bijective swizzle (gridDim.x % 8 == 0 for all launches here)
  const int cpx = (int)gridDim.x >> 3;
  int bid = (int)blockIdx.x;
  bid = (bid & 7) * cpx + (bid >> 3);
  const int tiles_n = N >> 8;
  const int tm0 = (bid / tiles_n) << 8;
  const int tn0 = (bid % tiles_n) << 8;

  // staging: tile = 256 rows x 32 u16 (16 KB), 1024 16B segs; thread t owns segs
  // t and t+512. Physical seg t -> row t>>2, slot t&3. Source slot = (t&3)^((t>>3)&3)
  // (row+128 preserves (row>>1)&3 since 64 = 0 mod 4).
  const int srow = t >> 2;
  const int scol = (((t & 3) ^ ((t >> 3) & 3)) << 3);  // u16 units
  const u16* Ag = A + (size_t)(tm0 + srow) * K + scol;
  const u16* Bg = B + (size_t)(tn0 + srow) * K + scol;
  u16* const ldsA = lds;
  u16* const ldsB = lds + 4 * 8192;

#define STAGE_A(slot_, kt_) do { \
    GLDS16(Ag + (kt_) * 32, ldsA + (slot_) * 8192 + t * 8); \
    GLDS16(Ag + (size_t)128 * K + (kt_) * 32, ldsA + (slot_) * 8192 + 4096 + t * 8); \
  } while (0)
#define STAGE_B(slot_, kt_) do { \
    GLDS16(Bg + (kt_) * 32, ldsB + (slot_) * 8192 + t * 8); \
    GLDS16(Bg + (size_t)128 * K + (kt_) * 32, ldsB + (slot_) * 8192 + 4096 + t * 8); \
  } while (0)

  // ds_read: row (base + frag*16 + lr), swizzled k-slot: pc u16 = (lk ^ ((lr>>1)&3))*8
  const int pc = (lk ^ ((lr >> 1) & 3)) * 8;
  const int rba = wm * 128 + lr;  // A row base
  const int rbb = wn * 64 + lr;   // B row base

  f32x4 acc[8][4] = {};
  const int nk = K >> 5;  // K-tiles (nk >= 8 for all layers)

  // prologue: stage tiles 0,1,2 (lead = 3)
  STAGE_A(0, 0); STAGE_B(0, 0);
  STAGE_A(1, 1); STAGE_B(1, 1);
  STAGE_A(2, 2); STAGE_B(2, 2);
  asm volatile("s_waitcnt vmcnt(8)" ::: "memory");  // tile 0 landed
  __builtin_amdgcn_s_barrier();

  for (int T = 0; T < nk; ++T) {
    const int sl = T & 3;
    const u16* la = ldsA + sl * 8192;
    const u16* lb = ldsB + sl * 8192;
    bf16x8 af[4], bf[4];
    // ---- phase 0: B frags (all 4) + A frags m=0..3 ----
#pragma unroll
    for (int n = 0; n < 4; ++n)
      bf[n] = *(const bf16x8*)(lb + (rbb + n * 16) * 32 + pc);
#pragma unroll
    for (int j = 0; j < 4; ++j)
      af[j] = *(const bf16x8*)(la + (rba + j * 16) * 32 + pc);
    if (T + 3 < nk) STAGE_A((T + 3) & 3, T + 3);
    __builtin_amdgcn_s_barrier();
    __builtin_amdgcn_s_setprio(1);
#pragma unroll
    for (int j = 0; j < 4; ++j)
#pragma unroll
      for (int n = 0; n < 4; ++n)
        acc[j][n] = __builtin_amdgcn_mfma_f32_16x16x32_bf16(af[j], bf[n], acc[j][n], 0, 0, 0);
    __builtin_amdgcn_s_setprio(0);
    // ---- phase 1: A frags m=4..7 (B reused in regs) ----
#pragma unroll
    for (int j = 0; j < 4; ++j)
      af[j] = *(const bf16x8*)(la + (rba + 64 + j * 16) * 32 + pc);
    if (T + 3 < nk) STAGE_B((T + 3) & 3, T + 3);
    // K-tile boundary wait: counted, never 0 mid-loop.
    if (T < nk - 3)       asm volatile("s_waitcnt vmcnt(8)" ::: "memory");
    else if (T == nk - 3) asm volatile("s_waitcnt vmcnt(4)" ::: "memory");
    else if (T == nk - 2) asm volatile("s_waitcnt vmcnt(0)" ::: "memory");
    __builtin_amdgcn_s_barrier();
    __builtin_amdgcn_s_setprio(1);
#pragma unroll
    for (int j = 0; j < 4; ++j)
#pragma unroll
      for (int n = 0; n < 4; ++n)
        acc[4 + j][n] = __builtin_amdgcn_mfma_f32_16x16x32_bf16(af[j], bf[n], acc[4 + j][n], 0, 0, 0);
    __builtin_amdgcn_s_setprio(0);
  }

  if (!DOMAX) {
    float cs[4] = {}, cq[4] = {};
#pragma unroll
    for (int n = 0; n < 4; ++n) {
      const int gcol = tn0 + wn * 64 + n * 16 + lr;
      const float cb = cp[gcol];
#pragma unroll
      for (int m = 0; m < 8; ++m) {
        const int grow = tm0 + wm * 128 + m * 16 + lk * 4;
#pragma unroll
        for (int r = 0; r < 4; ++r) {
          float v = acc[m][n][r] + cb;
          if (RELU) v = fmaxf(v, 0.f);
          Y[(size_t)(grow + r) * N + gcol] = f2bf(v);
          cs[n] += v;
          cq[n] += v * v;
        }
      }
    }
    if (RELU) {
#pragma unroll
      for (int n = 0; n < 4; ++n) {
        cs[n] += __shfl_xor(cs[n], 16, 64);
        cs[n] += __shfl_xor(cs[n], 32, 64);
        cq[n] += __shfl_xor(cq[n], 16, 64);
        cq[n] += __shfl_xor(cq[n], 32, 64);
      }
      float* sred = (float*)lds;  // [wm][256] sum | +512: [wm][256] sq
      __syncthreads();
      if (lk == 0) {
#pragma unroll
        for (int n = 0; n < 4; ++n) {
          const int c = wn * 64 + n * 16 + lr;
          sred[wm * 256 + c] = cs[n];
          sred[512 + wm * 256 + c] = cq[n];
        }
      }
      __syncthreads();
      if (t < 256) {
        atomicAdd(&osum[tn0 + t], sred[t] + sred[256 + t]);
      } else {
        const int c = t - 256;
        atomicAdd(&osq[tn0 + c], sred[512 + c] + sred[768 + c]);
      }
    }
  } else {
    // max-over-set epilogue: tile fully inside one batch (2048 % 256 == 0)
    const int batch = tm0 >> 11;
#pragma unroll
    for (int n = 0; n < 4; ++n) {
      const int gcol = tn0 + wn * 64 + n * 16 + lr;
      const float cb = cp[gcol];
      float mx = -3.0e38f;
#pragma unroll
      for (int m = 0; m < 8; ++m)
#pragma unroll
        for (int r = 0; r < 4; ++r)
          mx = fmaxf(mx, acc[m][n][r] + cb);
      mx = fmaxf(mx, __shfl_xor(mx, 16, 64));
      mx = fmaxf(mx, __shfl_xor(mx, 32, 64));
      if (lk == 0) {
        unsigned u = __builtin_bit_cast(unsigned, mx);
        u = (u & 0x80000000u) ? ~u : (u | 0x80000000u);
        atomicMax(&maxbuf[batch * N + gcol], u);
      }
    }
  }
#undef STAGE_A
#undef STAGE_B
}

__global__ void decode_k(const unsigned* __restrict__ mb, float* __restrict__ out, int n) {
  int i = blockIdx.x * 256 + threadIdx.x;
  if (i < n) {
    unsigned u = mb[i];
    u = (u & 0x80000000u) ? (u & 0x7FFFFFFFu) : ~u;
    out[i] = __builtin_bit_cast(float, u);
  }
}

extern "C" void kernel_launch(void* const* d_in, const int* in_sizes, int n_in,
                              void* d_out, int out_size, void* d_ws, size_t ws_size,
                              hipStream_t stream) {
  const float* x0 = (const float*)d_in[0];
  const float* g0 = (const float*)d_in[1];
  const float* b0 = (const float*)d_in[2];
  const float* W0 = (const float*)d_in[3];
  const float* c0 = (const float*)d_in[4];
  const float* g1 = (const float*)d_in[5];
  const float* b1 = (const float*)d_in[6];
  const float* W1 = (const float*)d_in[7];
  const float* c1 = (const float*)d_in[8];
  const float* g2 = (const float*)d_in[9];
  const float* b2 = (const float*)d_in[10];
  const float* W2 = (const float*)d_in[11];
  const float* c2 = (const float*)d_in[12];

  char* ws = (char*)d_ws;
  size_t off = 0;
  auto alloc = [&](size_t bytes) -> char* {
    char* p = ws + off;
    off += (bytes + 255) & ~(size_t)255;
    return p;
  };
  u16* x0bf = (u16*)alloc((size_t)MROWS * 256 * 2);
  u16* y1 = (u16*)alloc((size_t)MROWS * 512 * 2);
  u16* y2 = (u16*)alloc((size_t)MROWS * 512 * 2);
  // contiguous zero-init region: s0 replicas [NREP][512] | stats1 | stats2 | maxbuf
  float* s0rep = (float*)alloc((NREP * 512 + 1024 + 1024 + 32768) * 4);
  float* s1sum = s0rep + NREP * 512;
  float* s1sq = s1sum + 512;
  float* s2sum = s1sum + 1024;
  float* s2sq = s2sum + 512;
  unsigned* maxbuf = (unsigned*)(s1sum + 2048);
  const size_t zbytes = (size_t)(NREP * 512 + 2048 + 32768) * 4;
  u16* W0p = (u16*)alloc(512 * 256 * 2);
  u16* W1p = (u16*)alloc(512 * 512 * 2);
  u16* W2p = (u16*)alloc(1024 * 512 * 2);
  float* c0p = (float*)alloc(512 * 4);
  float* c1p = (float*)alloc(512 * 4);
  float* c2p = (float*)alloc(1024 * 4);
  if (off > ws_size) return;

  hipMemsetAsync(s0rep, 0, zbytes, stream);

  // layer 0 (epilogue produces layer-1 BN stats)
  stats_cast_k<<<2048, 256, 0, stream>>>(x0, x0bf, s0rep);
  prep_w_k<<<128, 256, 0, stream>>>(W0, g0, b0, c0, s0rep, s0rep + 256, 512, NREP,
                                    W0p, c0p, 256, 512);
  gemm_k<true, false><<<512, 512, 0, stream>>>(x0bf, W0p, c0p, y1, s1sum, s1sq, nullptr, 256, 512);
  // layer 1 (epilogue produces layer-2 BN stats)
  prep_w_k<<<128, 256, 0, stream>>>(W1, g1, b1, c1, s1sum, s1sq, 0, 1,
                                    W1p, c1p, 512, 512);
  gemm_k<true, false><<<512, 512, 0, stream>>>(y1, W1p, c1p, y2, s2sum, s2sq, nullptr, 512, 512);
  // layer 2 + max reduction
  prep_w_k<<<256, 256, 0, stream>>>(W2, g2, b2, c2, s2sum, s2sq, 0, 1,
                                    W2p, c2p, 512, 1024);
  gemm_k<false, true><<<1024, 512, 0, stream>>>(y2, W2p, c2p, nullptr, nullptr, nullptr, maxbuf, 512, 1024);
  decode_k<<<128, 256, 0, stream>>>(maxbuf, (float*)d_out, 32768);
}